// Round 6
// baseline (221.240 us; speedup 1.0000x reference)
//
#include <hip/hip_runtime.h>

#define BATCH 64
#define TLEN  512
#define HDIM  768
#define LTAGS 9

// Workspace layout (bytes)
#define WS_LOGD 0                        // f64 [32768][9] = 2359296
#define WS_VM   2359296                  // f64 [64][64][9][10] padded = 2949120
#define WS_AM   5308416                  // f32 [64][32][9][9] = 663552
#define WS_NUM  5971968                  // f64 [64]

// ---------------------------------------------------------------------------
// Kernel A: logits = hidden @ W^T + b.  f32 dot4 segments accumulated in f64.
// (identical numerics to rounds 2-5; validated absmax 0.0)
// ---------------------------------------------------------------------------
__global__ __launch_bounds__(256) void logits_kernel(
    const float* __restrict__ hidden, const float* __restrict__ W,
    const float* __restrict__ bvec, double* __restrict__ logitsD)
{
    __shared__ float sW[LTAGS * HDIM];
    __shared__ float sb[LTAGS];
    const int tid = threadIdx.x;
    for (int i = tid; i < LTAGS * HDIM; i += 256) sW[i] = W[i];
    if (tid < LTAGS) sb[tid] = bvec[tid];
    __syncthreads();

    const int lane = tid & 63;
    const int wave = tid >> 6;
    const int sub  = lane & 7;
    const int rg   = lane >> 3;

    const int rowBase = blockIdx.x * 64 + wave * 16;
    const int r0 = rowBase + rg;
    const int r1 = rowBase + rg + 8;
    const float* h0p = hidden + (size_t)r0 * HDIM;
    const float* h1p = hidden + (size_t)r1 * HDIM;

    double acc0[LTAGS], acc1[LTAGS];
    #pragma unroll
    for (int l = 0; l < LTAGS; ++l) { acc0[l] = 0.0; acc1[l] = 0.0; }

    #pragma unroll 2
    for (int i = 0; i < 24; ++i) {
        const int off = i * 32 + sub * 4;
        const float4 h0 = *(const float4*)(h0p + off);
        const float4 h1 = *(const float4*)(h1p + off);
        #pragma unroll
        for (int l = 0; l < LTAGS; ++l) {
            const float4 w = *(const float4*)&sW[l * HDIM + off];
            float d0 = h0.x * w.x;
            d0 = fmaf(h0.y, w.y, d0); d0 = fmaf(h0.z, w.z, d0); d0 = fmaf(h0.w, w.w, d0);
            float d1 = h1.x * w.x;
            d1 = fmaf(h1.y, w.y, d1); d1 = fmaf(h1.z, w.z, d1); d1 = fmaf(h1.w, w.w, d1);
            acc0[l] += (double)d0;
            acc1[l] += (double)d1;
        }
    }
    #pragma unroll
    for (int l = 0; l < LTAGS; ++l) {
        double v0 = acc0[l], v1 = acc1[l];
        #pragma unroll
        for (int off = 4; off > 0; off >>= 1) {
            v0 += __shfl_down(v0, off);
            v1 += __shfl_down(v1, off);
        }
        acc0[l] = v0; acc1[l] = v1;
    }
    if (sub == 0) {
        #pragma unroll
        for (int l = 0; l < LTAGS; ++l) {
            logitsD[(size_t)r0 * LTAGS + l] = acc0[l] + (double)sb[l];
            logitsD[(size_t)r1 * LTAGS + l] = acc1[l] + (double)sb[l];
        }
    }
}

// ---------------------------------------------------------------------------
// Kernel B1 (chunk): 232 blocks x 256 threads.  Same math as R5 (bit-exact);
// Viterbi chunk mats now written PADDED: [b][c][i][10] f64 (16B-aligned rows).
// ---------------------------------------------------------------------------
__global__ __launch_bounds__(256) void chunk_kernel(
    const float* __restrict__ trans, const int* __restrict__ labels,
    const int* __restrict__ att, const double* __restrict__ logitsD,
    double* __restrict__ wsVM, float* __restrict__ wsAM,
    double* __restrict__ wsNum, float* __restrict__ out)
{
    __shared__ __align__(16) double sT64[90];   // padded k*10+j
    __shared__ __align__(16) float  sE32[108];  // padded k*12+j
    const int tid = threadIdx.x;
    if (tid < 81) {
        const int k = tid / 9, j = tid - 9 * k;
        float tv = trans[tid];
        sT64[k * 10 + j] = (double)tv;
        sE32[k * 12 + j] = __expf(tv);
    }
    if (blockIdx.x == 0 && tid == 0) out[0] = 0.f;   // init for atomic loss
    __syncthreads();

    const int blk = blockIdx.x;
    if (blk < 144) {
        // ---- Viterbi chunk rows ----
        const int gid = blk * 256 + tid;
        const int b   = gid / 576;
        const int rem = gid - b * 576;
        const int c   = rem / 9;
        const int i   = rem - c * 9;

        double M[LTAGS];
        #pragma unroll
        for (int j = 0; j < LTAGS; ++j) M[j] = (i == j) ? 0.0 : -1e300;

        const double* lrow = logitsD + ((size_t)b * TLEN + (c * 8 + 1)) * LTAGS;
        const int* lab = labels + b * TLEN;
        const int* am  = att + b * TLEN;
        const int t0 = c * 8 + 1;

        double lg[LTAGS], lgN[LTAGS];
        #pragma unroll
        for (int j = 0; j < LTAGS; ++j) lg[j] = lrow[j];
        bool mk = (am[t0] != 0) && (lab[t0] != -100);

        for (int s = 0; s < 8; ++s) {
            bool mkN = false;
            const int tn = t0 + s + 1;
            if (s < 7 && tn <= TLEN - 1) {
                const double* ln = lrow + (s + 1) * LTAGS;
                #pragma unroll
                for (int j = 0; j < LTAGS; ++j) lgN[j] = ln[j];
                mkN = (am[tn] != 0) && (lab[tn] != -100);
            }
            double nw[LTAGS];
            #pragma unroll
            for (int k = 0; k < LTAGS; ++k) {
                const double2* r = (const double2*)&sT64[k * 10];
                const double2 r01 = r[0], r23 = r[1], r45 = r[2], r67 = r[3];
                const double r8 = sT64[k * 10 + 8];
                const double mk64 = M[k];
                if (k == 0) {
                    nw[0] = mk64 + r01.x; nw[1] = mk64 + r01.y;
                    nw[2] = mk64 + r23.x; nw[3] = mk64 + r23.y;
                    nw[4] = mk64 + r45.x; nw[5] = mk64 + r45.y;
                    nw[6] = mk64 + r67.x; nw[7] = mk64 + r67.y;
                    nw[8] = mk64 + r8;
                } else {
                    nw[0] = fmax(nw[0], mk64 + r01.x); nw[1] = fmax(nw[1], mk64 + r01.y);
                    nw[2] = fmax(nw[2], mk64 + r23.x); nw[3] = fmax(nw[3], mk64 + r23.y);
                    nw[4] = fmax(nw[4], mk64 + r45.x); nw[5] = fmax(nw[5], mk64 + r45.y);
                    nw[6] = fmax(nw[6], mk64 + r67.x); nw[7] = fmax(nw[7], mk64 + r67.y);
                    nw[8] = fmax(nw[8], mk64 + r8);
                }
            }
            #pragma unroll
            for (int j = 0; j < LTAGS; ++j) {
                M[j] = mk ? (nw[j] + lg[j]) : M[j];
                lg[j] = lgN[j];
            }
            mk = mkN;
        }
        double* dst = wsVM + ((size_t)b * 64 + c) * 90 + (size_t)i * 10;
        #pragma unroll
        for (int j = 0; j < LTAGS; ++j) dst[j] = M[j];
    } else if (blk < 216) {
        // ---- alpha chunk rows (unchanged) ----
        const int gid = (blk - 144) * 256 + tid;
        const int b   = gid / 288;
        const int rem = gid - b * 288;
        const int c   = rem / 9;
        const int i   = rem - c * 9;

        float M[LTAGS];
        #pragma unroll
        for (int j = 0; j < LTAGS; ++j) M[j] = (i == j) ? 0.f : -1e30f;

        const double* lrow = logitsD + ((size_t)b * TLEN + (c * 16 + 1)) * LTAGS;
        const int* lab = labels + b * TLEN;
        const int* am  = att + b * TLEN;
        const int t0 = c * 16 + 1;

        float lg[LTAGS], lgN[LTAGS];
        #pragma unroll
        for (int j = 0; j < LTAGS; ++j) lg[j] = (float)lrow[j];
        bool mk = (am[t0] != 0) && (lab[t0] != -100);

        for (int s = 0; s < 16; ++s) {
            bool mkN = false;
            const int tn = t0 + s + 1;
            if (s < 15 && tn <= TLEN - 1) {
                const double* ln = lrow + (s + 1) * LTAGS;
                #pragma unroll
                for (int j = 0; j < LTAGS; ++j) lgN[j] = (float)ln[j];
                mkN = (am[tn] != 0) && (lab[tn] != -100);
            }
            float m = M[0];
            #pragma unroll
            for (int k = 1; k < LTAGS; ++k) m = fmaxf(m, M[k]);
            float P[LTAGS];
            #pragma unroll
            for (int k = 0; k < LTAGS; ++k) P[k] = __expf(M[k] - m);
            float sa[LTAGS];
            #pragma unroll
            for (int k = 0; k < LTAGS; ++k) {
                const float4* r = (const float4*)&sE32[k * 12];
                const float4 f03 = r[0], f47 = r[1];
                const float f8 = sE32[k * 12 + 8];
                const float pk = P[k];
                if (k == 0) {
                    sa[0] = pk * f03.x; sa[1] = pk * f03.y; sa[2] = pk * f03.z; sa[3] = pk * f03.w;
                    sa[4] = pk * f47.x; sa[5] = pk * f47.y; sa[6] = pk * f47.z; sa[7] = pk * f47.w;
                    sa[8] = pk * f8;
                } else {
                    sa[0] = fmaf(pk, f03.x, sa[0]); sa[1] = fmaf(pk, f03.y, sa[1]);
                    sa[2] = fmaf(pk, f03.z, sa[2]); sa[3] = fmaf(pk, f03.w, sa[3]);
                    sa[4] = fmaf(pk, f47.x, sa[4]); sa[5] = fmaf(pk, f47.y, sa[5]);
                    sa[6] = fmaf(pk, f47.z, sa[6]); sa[7] = fmaf(pk, f47.w, sa[7]);
                    sa[8] = fmaf(pk, f8,    sa[8]);
                }
            }
            #pragma unroll
            for (int j = 0; j < LTAGS; ++j) {
                float nwj = m + __logf(sa[j]) + lg[j];
                M[j] = mk ? nwj : M[j];
                lg[j] = lgN[j];
            }
            mk = mkN;
        }
        float* dst = wsAM + (((size_t)b * 32 + c) * LTAGS + i) * LTAGS;
        #pragma unroll
        for (int j = 0; j < LTAGS; ++j) dst[j] = M[j];
    } else {
        // ---- numerator: one wave per batch ----
        const int bb   = (blk - 216) * 4 + (tid >> 6);
        const int lane = tid & 63;
        const int* lab = labels + bb * TLEN;
        const int* am  = att + bb * TLEN;
        const double* lrowb = logitsD + (size_t)bb * TLEN * LTAGS;
        double part = 0.0;
        #pragma unroll
        for (int k = 0; k < 8; ++k) {
            const int t = lane + k * 64;
            int lv = lab[t], av = am[t];
            bool mkc = (av != 0) && (lv != -100);
            int tg = (lv == -100) ? 0 : lv;
            if (mkc) part += lrowb[(size_t)t * LTAGS + tg];
            if (t < TLEN - 1) {
                int lv2 = lab[t + 1], av2 = am[t + 1];
                bool mk2 = (av2 != 0) && (lv2 != -100);
                int tg2 = (lv2 == -100) ? 0 : lv2;
                if (mk2) part += sT64[tg * 10 + tg2];
            }
        }
        #pragma unroll
        for (int off = 32; off > 0; off >>= 1) part += __shfl_down(part, off);
        if (lane == 0) wsNum[bb] = part;
    }
}

// ---------------------------------------------------------------------------
// Kernel B2 (crf2): per-batch block, 128 threads.
//  stage -> super-mats (8 products of 8 chunk mats, threads 0..71)
//  wave0: replicated 8-step super-scan (broadcast LDS, NO shfl) with per-lane
//         snapshot -> <=7 catch-up mat-vecs -> replay+backpointers ->
//         shfl-suffix backtrace -> predictions
//  wave1: alpha boundary scan (unchanged from R5) -> denominator
// ---------------------------------------------------------------------------
__global__ __launch_bounds__(128) void crf2_kernel(
    const float* __restrict__ trans, const int* __restrict__ labels,
    const int* __restrict__ att, const double* __restrict__ logitsD,
    const double* __restrict__ wsVM, const float* __restrict__ wsAM,
    const double* __restrict__ wsNum, float* __restrict__ out)
{
    __shared__ __align__(16) double sVM[64 * 90];          // 46080 B (padded rows)
    __shared__ __align__(16) float  sAM[32 * 81];          // 10368 B
    __shared__ __align__(16) double sU[720];               // 5760 B: sSM, then sBPp
    __shared__ __align__(16) double sT64[90];              // padded k*10+j
    __shared__ unsigned char sMk[513];
    __shared__ int sTagB[65];
    __shared__ double sDen;

    const int b = blockIdx.x, tid = threadIdx.x;
    const int wave = tid >> 6, lane = tid & 63;
    const unsigned long long IDMAP = 0x876543210ull;

    // ---- stage (coalesced) ----
    const double2* gVM = (const double2*)(wsVM + (size_t)b * 5760);
    double2* sVM2 = (double2*)sVM;
    for (int i = tid; i < 2880; i += 128) sVM2[i] = gVM[i];
    const float4* gAM = (const float4*)(wsAM + (size_t)b * 2592);
    float4* sAM4 = (float4*)sAM;
    for (int i = tid; i < 648; i += 128) sAM4[i] = gAM[i];

    const int* lab = labels + b * TLEN;
    const int* am  = att + b * TLEN;
    for (int t = tid; t < TLEN; t += 128) {
        int lv = lab[t], av = am[t];
        sMk[t] = (av != 0 && lv != -100) ? 1 : 0;
    }
    if (tid == 0) sMk[TLEN] = 0;
    if (tid < 81) {
        const int k = tid / 9, j = tid - 9 * k;
        sT64[k * 10 + j] = (double)trans[tid];
    }
    __syncthreads();

    // ---- super-mats: S_g = M_{8g} (x) ... (x) M_{8g+7}, row-wise ----
    double* sSM = sU;
    if (tid < 72) {
        const int g = tid / 9, i = tid - 9 * g;
        double P[LTAGS];
        {
            const double* row = &sVM[(g * 8) * 90 + i * 10];
            #pragma unroll
            for (int j = 0; j < LTAGS; ++j) P[j] = row[j];
        }
        for (int m = g * 8 + 1; m < g * 8 + 8; ++m) {
            double np[LTAGS];
            #pragma unroll
            for (int k = 0; k < LTAGS; ++k) {
                const double2* r = (const double2*)&sVM[m * 90 + k * 10];
                const double2 r01 = r[0], r23 = r[1], r45 = r[2], r67 = r[3];
                const double r8 = sVM[m * 90 + k * 10 + 8];
                const double pk = P[k];
                if (k == 0) {
                    np[0] = pk + r01.x; np[1] = pk + r01.y;
                    np[2] = pk + r23.x; np[3] = pk + r23.y;
                    np[4] = pk + r45.x; np[5] = pk + r45.y;
                    np[6] = pk + r67.x; np[7] = pk + r67.y;
                    np[8] = pk + r8;
                } else {
                    np[0] = fmax(np[0], pk + r01.x); np[1] = fmax(np[1], pk + r01.y);
                    np[2] = fmax(np[2], pk + r23.x); np[3] = fmax(np[3], pk + r23.y);
                    np[4] = fmax(np[4], pk + r45.x); np[5] = fmax(np[5], pk + r45.y);
                    np[6] = fmax(np[6], pk + r67.x); np[7] = fmax(np[7], pk + r67.y);
                    np[8] = fmax(np[8], pk + r8);
                }
            }
            #pragma unroll
            for (int j = 0; j < LTAGS; ++j) P[j] = np[j];
        }
        double* dst = &sSM[g * 90 + i * 10];
        #pragma unroll
        for (int j = 0; j < LTAGS; ++j) dst[j] = P[j];
    }
    __syncthreads();

    unsigned long long* sBPp = (unsigned long long*)sU;   // reused after super-scan
    unsigned long long S = IDMAP;
    int lastTag = 0;

    if (wave == 0) {
        const int c = lane;             // chunk owned by this lane
        const int myg = c >> 3;
        double v[LTAGS], vS[LTAGS];
        #pragma unroll
        for (int j = 0; j < LTAGS; ++j) v[j] = logitsD[(size_t)b * TLEN * LTAGS + j];

        // ---- replicated super-scan (8 steps, broadcast LDS, no shfl) ----
        #pragma unroll
        for (int g = 0; g < 8; ++g) {
            if (g == myg) {
                #pragma unroll
                for (int j = 0; j < LTAGS; ++j) vS[j] = v[j];
            }
            double nv[LTAGS];
            #pragma unroll
            for (int k = 0; k < LTAGS; ++k) {
                const double2* r = (const double2*)&sSM[g * 90 + k * 10];
                const double2 r01 = r[0], r23 = r[1], r45 = r[2], r67 = r[3];
                const double r8 = sSM[g * 90 + k * 10 + 8];
                const double vk = v[k];
                if (k == 0) {
                    nv[0] = vk + r01.x; nv[1] = vk + r01.y;
                    nv[2] = vk + r23.x; nv[3] = vk + r23.y;
                    nv[4] = vk + r45.x; nv[5] = vk + r45.y;
                    nv[6] = vk + r67.x; nv[7] = vk + r67.y;
                    nv[8] = vk + r8;
                } else {
                    nv[0] = fmax(nv[0], vk + r01.x); nv[1] = fmax(nv[1], vk + r01.y);
                    nv[2] = fmax(nv[2], vk + r23.x); nv[3] = fmax(nv[3], vk + r23.y);
                    nv[4] = fmax(nv[4], vk + r45.x); nv[5] = fmax(nv[5], vk + r45.y);
                    nv[6] = fmax(nv[6], vk + r67.x); nv[7] = fmax(nv[7], vk + r67.y);
                    nv[8] = fmax(nv[8], vk + r8);
                }
            }
            #pragma unroll
            for (int j = 0; j < LTAGS; ++j) v[j] = nv[j];
        }
        // last tag (identical in every lane): argmax, ties -> lowest
        {
            int bi = 0; double bv = v[0];
            #pragma unroll
            for (int i = 1; i < LTAGS; ++i) if (v[i] > bv) { bv = v[i]; bi = i; }
            lastTag = bi;
        }

        // ---- catch-up: apply chunk mats 8*myg .. c-1 (<=7, per-lane) ----
        const int nCat = c & 7;
        for (int it = 0; it < nCat; ++it) {
            const int m = (c & ~7) + it;
            double nv[LTAGS];
            #pragma unroll
            for (int k = 0; k < LTAGS; ++k) {
                const double2* r = (const double2*)&sVM[m * 90 + k * 10];
                const double2 r01 = r[0], r23 = r[1], r45 = r[2], r67 = r[3];
                const double r8 = sVM[m * 90 + k * 10 + 8];
                const double vk = vS[k];
                if (k == 0) {
                    nv[0] = vk + r01.x; nv[1] = vk + r01.y;
                    nv[2] = vk + r23.x; nv[3] = vk + r23.y;
                    nv[4] = vk + r45.x; nv[5] = vk + r45.y;
                    nv[6] = vk + r67.x; nv[7] = vk + r67.y;
                    nv[8] = vk + r8;
                } else {
                    nv[0] = fmax(nv[0], vk + r01.x); nv[1] = fmax(nv[1], vk + r01.y);
                    nv[2] = fmax(nv[2], vk + r23.x); nv[3] = fmax(nv[3], vk + r23.y);
                    nv[4] = fmax(nv[4], vk + r45.x); nv[5] = fmax(nv[5], vk + r45.y);
                    nv[6] = fmax(nv[6], vk + r67.x); nv[7] = fmax(nv[7], vk + r67.y);
                    nv[8] = fmax(nv[8], vk + r8);
                }
            }
            #pragma unroll
            for (int j = 0; j < LTAGS; ++j) vS[j] = nv[j];
        }

        // ---- replay: backpointers + per-chunk composed map ----
        const double* lrow = logitsD + ((size_t)b * TLEN + (c * 8 + 1)) * LTAGS;
        double lg[LTAGS], lgN[LTAGS];
        #pragma unroll
        for (int j = 0; j < LTAGS; ++j) lg[j] = lrow[j];

        for (int s = 0; s < 8; ++s) {
            const int t = c * 8 + 1 + s;
            if (s < 7 && t + 1 <= TLEN - 1) {
                const double* ln = lrow + (s + 1) * LTAGS;
                #pragma unroll
                for (int j = 0; j < LTAGS; ++j) lgN[j] = ln[j];
            }
            const bool mk = (sMk[t] != 0);
            double bst[LTAGS];
            int bi[LTAGS];
            #pragma unroll
            for (int k = 0; k < LTAGS; ++k) {
                const double2* r = (const double2*)&sT64[k * 10];
                const double2 r01 = r[0], r23 = r[1], r45 = r[2], r67 = r[3];
                const double r8 = sT64[k * 10 + 8];
                const double vk = vS[k];
                double cnd[LTAGS];
                cnd[0] = vk + r01.x; cnd[1] = vk + r01.y;
                cnd[2] = vk + r23.x; cnd[3] = vk + r23.y;
                cnd[4] = vk + r45.x; cnd[5] = vk + r45.y;
                cnd[6] = vk + r67.x; cnd[7] = vk + r67.y;
                cnd[8] = vk + r8;
                if (k == 0) {
                    #pragma unroll
                    for (int j = 0; j < LTAGS; ++j) { bst[j] = cnd[j]; bi[j] = 0; }
                } else {
                    #pragma unroll
                    for (int j = 0; j < LTAGS; ++j) {
                        bool gt = cnd[j] > bst[j];     // strict >: ties keep lowest k
                        bst[j] = gt ? cnd[j] : bst[j];
                        bi[j]  = gt ? k : bi[j];
                    }
                }
            }
            unsigned long long pk = 0;
            #pragma unroll
            for (int j = 0; j < LTAGS; ++j)
                pk |= ((unsigned long long)bi[j]) << (4 * j);
            pk = mk ? pk : IDMAP;
            sBPp[t] = pk;
            #pragma unroll
            for (int j = 0; j < LTAGS; ++j) {
                vS[j] = mk ? (bst[j] + lg[j]) : vS[j];
                lg[j] = lgN[j];
            }
        }
        // compose chunk backtrace map
        unsigned long long G = IDMAP;
        for (int s = 7; s >= 0; --s) {
            const unsigned long long bp = sBPp[c * 8 + 1 + s];
            unsigned long long ng = 0;
            #pragma unroll
            for (int j = 0; j < LTAGS; ++j) {
                int gj = (int)((G >> (4 * j)) & 15);
                int f  = (int)((bp >> (4 * gj)) & 15);
                ng |= ((unsigned long long)f) << (4 * j);
            }
            G = ng;
        }
        S = G;
    } else {
        // ---- alpha boundary scan over 32 chunk matrices (unchanged R5) ----
        const int j = (lane < LTAGS) ? lane : (LTAGS - 1);
        float v = (float)logitsD[(size_t)b * TLEN * LTAGS + j];
        float Mc[LTAGS], Mn[LTAGS];
        #pragma unroll
        for (int i = 0; i < LTAGS; ++i) Mc[i] = sAM[i * LTAGS + j];
        for (int c = 0; c < 32; ++c) {
            if (c < 31) {
                #pragma unroll
                for (int i = 0; i < LTAGS; ++i) Mn[i] = sAM[(c + 1) * 81 + i * LTAGS + j];
            }
            float g[LTAGS];
            #pragma unroll
            for (int i = 0; i < LTAGS; ++i) g[i] = __shfl(v, i);
            float a[LTAGS];
            #pragma unroll
            for (int i = 0; i < LTAGS; ++i) a[i] = g[i] + Mc[i];
            float t01 = fmaxf(a[0], a[1]), t23 = fmaxf(a[2], a[3]);
            float t45 = fmaxf(a[4], a[5]), t67 = fmaxf(a[6], a[7]);
            float m = fmaxf(fmaxf(fmaxf(t01, t23), fmaxf(t45, t67)), a[8]);
            float sacc = 0.f;
            #pragma unroll
            for (int i = 0; i < LTAGS; ++i) sacc += __expf(a[i] - m);
            v = m + __logf(sacc);
            if (c < 31) {
                #pragma unroll
                for (int i = 0; i < LTAGS; ++i) Mc[i] = Mn[i];
            }
        }
        float g[LTAGS];
        #pragma unroll
        for (int i = 0; i < LTAGS; ++i) g[i] = __shfl(v, i);
        if (lane == 0) {
            float m = g[0];
            #pragma unroll
            for (int i = 1; i < LTAGS; ++i) m = fmaxf(m, g[i]);
            float sacc = 0.f;
            #pragma unroll
            for (int i = 0; i < LTAGS; ++i) sacc += __expf(g[i] - m);
            sDen = (double)(m + __logf(sacc));
        }
    }

    // ---- suffix composition scan via shfl: S_c = F_c o ... o F_63 ----
    #pragma unroll
    for (int d = 1; d < 64; d <<= 1) {
        unsigned long long Sn = __shfl_down(S, d);
        if (wave == 0 && lane + d < 64) {
            unsigned long long R = 0;
            #pragma unroll
            for (int x = 0; x < LTAGS; ++x) {
                int y = (int)((Sn >> (4 * x)) & 15);
                int z = (int)((S >> (4 * y)) & 15);
                R |= ((unsigned long long)z) << (4 * x);
            }
            S = R;
        }
    }
    if (wave == 0) {
        sTagB[tid] = (int)((S >> (4 * lastTag)) & 15);
        if (tid == 0) sTagB[64] = lastTag;
    }
    __syncthreads();

    // ---- chunk-parallel expansion -> predictions ----
    if (tid < 64) {
        const int c = tid;
        int cur = sTagB[c + 1];
        float* po = out + 1 + b * TLEN;
        for (int s = 8; s >= 1; --s) {
            const int t = c * 8 + s;
            if (t < TLEN) {
                int nxt = (int)((sBPp[t] >> (4 * cur)) & 15);
                po[t] = sMk[t - 1] ? (float)nxt : -100.f;
                cur = nxt;
            }
        }
    }
    if (tid == 0) {
        out[1 + b * TLEN] = -100.f;
        atomicAdd(out, (float)(sDen - wsNum[b]));   // loss (den - num)
    }
}

extern "C" void kernel_launch(void* const* d_in, const int* in_sizes, int n_in,
                              void* d_out, int out_size, void* d_ws, size_t ws_size,
                              hipStream_t stream)
{
    const float* hidden = (const float*)d_in[0];
    const float* W      = (const float*)d_in[1];
    const float* bvec   = (const float*)d_in[2];
    const float* trans  = (const float*)d_in[3];
    const int*   labels = (const int*)d_in[4];
    const int*   att    = (const int*)d_in[5];
    float* out = (float*)d_out;

    char* ws = (char*)d_ws;
    double* logitsD = (double*)(ws + WS_LOGD);
    double* wsVM    = (double*)(ws + WS_VM);
    float*  wsAM    = (float*)(ws + WS_AM);
    double* wsNum   = (double*)(ws + WS_NUM);

    logits_kernel<<<512, 256, 0, stream>>>(hidden, W, bvec, logitsD);
    chunk_kernel<<<232, 256, 0, stream>>>(trans, labels, att, logitsD,
                                          wsVM, wsAM, wsNum, out);
    crf2_kernel<<<BATCH, 128, 0, stream>>>(trans, labels, att, logitsD,
                                           wsVM, wsAM, wsNum, out);
}

// Round 7
// 219.237 us; speedup vs baseline: 1.0091x; 1.0091x over previous
//
#include <hip/hip_runtime.h>

#define BATCH 64
#define TLEN  512
#define HDIM  768
#define LTAGS 9

// Workspace layout (bytes)
#define WS_LOGD 0                        // f64 [32768][9] = 2359296
#define WS_VM   2359296                  // f64 [64][64][9][10] padded = 2949120
#define WS_AM   5308416                  // f32 [64][32][9][9] = 663552
#define WS_NUMP 5971968                  // f64 [64][8] = 4096

// XCD-affinity block mapping (gfx950: blockIdx -> XCD is round-robin %8).
// All blocks touching batch b have blockIdx % 8 == b % 8, so the
// logits -> chunk -> crf2 dataflow for a batch stays in one XCD's L2.
// 512-block kernels: res=B&7, m=B>>3, b=8*(m>>3)+res, j=m&7  (j = window 0..7)

// ---------------------------------------------------------------------------
// Kernel A: logits = hidden @ W^T + b.  f32 dot4 segments accumulated in f64.
// (identical numerics to rounds 2-6; validated absmax 0.0).  XCD-swizzled.
// ---------------------------------------------------------------------------
__global__ __launch_bounds__(256) void logits_kernel(
    const float* __restrict__ hidden, const float* __restrict__ W,
    const float* __restrict__ bvec, double* __restrict__ logitsD,
    float* __restrict__ out)
{
    __shared__ float sW[LTAGS * HDIM];
    __shared__ float sb[LTAGS];
    const int tid = threadIdx.x;
    for (int i = tid; i < LTAGS * HDIM; i += 256) sW[i] = W[i];
    if (tid < LTAGS) sb[tid] = bvec[tid];
    if (blockIdx.x == 0 && tid == 0) out[0] = 0.f;   // init for atomic loss
    __syncthreads();

    const int lane = tid & 63;
    const int wave = tid >> 6;
    const int sub  = lane & 7;
    const int rg   = lane >> 3;

    const int B   = blockIdx.x;
    const int res = B & 7, mq = B >> 3;
    const int b   = ((mq >> 3) << 3) + res;     // batch owning this block
    const int jw  = mq & 7;                     // 64-row window within batch

    const int rowBase = b * TLEN + jw * 64 + wave * 16;
    const int r0 = rowBase + rg;
    const int r1 = rowBase + rg + 8;
    const float* h0p = hidden + (size_t)r0 * HDIM;
    const float* h1p = hidden + (size_t)r1 * HDIM;

    double acc0[LTAGS], acc1[LTAGS];
    #pragma unroll
    for (int l = 0; l < LTAGS; ++l) { acc0[l] = 0.0; acc1[l] = 0.0; }

    #pragma unroll 2
    for (int i = 0; i < 24; ++i) {
        const int off = i * 32 + sub * 4;
        const float4 h0 = *(const float4*)(h0p + off);
        const float4 h1 = *(const float4*)(h1p + off);
        #pragma unroll
        for (int l = 0; l < LTAGS; ++l) {
            const float4 w = *(const float4*)&sW[l * HDIM + off];
            float d0 = h0.x * w.x;
            d0 = fmaf(h0.y, w.y, d0); d0 = fmaf(h0.z, w.z, d0); d0 = fmaf(h0.w, w.w, d0);
            float d1 = h1.x * w.x;
            d1 = fmaf(h1.y, w.y, d1); d1 = fmaf(h1.z, w.z, d1); d1 = fmaf(h1.w, w.w, d1);
            acc0[l] += (double)d0;
            acc1[l] += (double)d1;
        }
    }
    #pragma unroll
    for (int l = 0; l < LTAGS; ++l) {
        double v0 = acc0[l], v1 = acc1[l];
        #pragma unroll
        for (int off = 4; off > 0; off >>= 1) {
            v0 += __shfl_down(v0, off);
            v1 += __shfl_down(v1, off);
        }
        acc0[l] = v0; acc1[l] = v1;
    }
    if (sub == 0) {
        #pragma unroll
        for (int l = 0; l < LTAGS; ++l) {
            logitsD[(size_t)r0 * LTAGS + l] = acc0[l] + (double)sb[l];
            logitsD[(size_t)r1 * LTAGS + l] = acc1[l] + (double)sb[l];
        }
    }
}

// ---------------------------------------------------------------------------
// Kernel B1 (chunk): 512 blocks x 256 threads, batch-affine (8 blocks/batch).
//   threads 0..71:    Viterbi chunk rows, chunks jw*8..jw*8+7 (f64, 8 steps)
//   threads 128..163: alpha chunk rows, chunks jw*4..jw*4+3 (f32, 16 steps)
//   threads 192..255: numerator partial over t-window [jw*64, jw*64+64)
// Per-thread math identical to R6 (bit-exact).
// ---------------------------------------------------------------------------
__global__ __launch_bounds__(256) void chunk_kernel(
    const float* __restrict__ trans, const int* __restrict__ labels,
    const int* __restrict__ att, const double* __restrict__ logitsD,
    double* __restrict__ wsVM, float* __restrict__ wsAM,
    double* __restrict__ wsNumP)
{
    __shared__ __align__(16) double sT64[90];   // padded k*10+j
    __shared__ __align__(16) float  sE32[108];  // padded k*12+j
    const int tid = threadIdx.x;
    if (tid < 81) {
        const int k = tid / 9, j = tid - 9 * k;
        float tv = trans[tid];
        sT64[k * 10 + j] = (double)tv;
        sE32[k * 12 + j] = __expf(tv);
    }
    __syncthreads();

    const int B   = blockIdx.x;
    const int res = B & 7, mq = B >> 3;
    const int b   = ((mq >> 3) << 3) + res;
    const int jw  = mq & 7;

    const int* lab = labels + b * TLEN;
    const int* am  = att + b * TLEN;

    if (tid < 72) {
        // ---- Viterbi chunk rows ----
        const int cl = tid / 9, i = tid - 9 * cl;
        const int c  = jw * 8 + cl;

        double M[LTAGS];
        #pragma unroll
        for (int j = 0; j < LTAGS; ++j) M[j] = (i == j) ? 0.0 : -1e300;

        const double* lrow = logitsD + ((size_t)b * TLEN + (c * 8 + 1)) * LTAGS;
        const int t0 = c * 8 + 1;

        double lg[LTAGS], lgN[LTAGS];
        #pragma unroll
        for (int j = 0; j < LTAGS; ++j) lg[j] = lrow[j];
        bool mk = (am[t0] != 0) && (lab[t0] != -100);

        for (int s = 0; s < 8; ++s) {
            bool mkN = false;
            const int tn = t0 + s + 1;
            if (s < 7 && tn <= TLEN - 1) {
                const double* ln = lrow + (s + 1) * LTAGS;
                #pragma unroll
                for (int j = 0; j < LTAGS; ++j) lgN[j] = ln[j];
                mkN = (am[tn] != 0) && (lab[tn] != -100);
            }
            double nw[LTAGS];
            #pragma unroll
            for (int k = 0; k < LTAGS; ++k) {
                const double2* r = (const double2*)&sT64[k * 10];
                const double2 r01 = r[0], r23 = r[1], r45 = r[2], r67 = r[3];
                const double r8 = sT64[k * 10 + 8];
                const double mk64 = M[k];
                if (k == 0) {
                    nw[0] = mk64 + r01.x; nw[1] = mk64 + r01.y;
                    nw[2] = mk64 + r23.x; nw[3] = mk64 + r23.y;
                    nw[4] = mk64 + r45.x; nw[5] = mk64 + r45.y;
                    nw[6] = mk64 + r67.x; nw[7] = mk64 + r67.y;
                    nw[8] = mk64 + r8;
                } else {
                    nw[0] = fmax(nw[0], mk64 + r01.x); nw[1] = fmax(nw[1], mk64 + r01.y);
                    nw[2] = fmax(nw[2], mk64 + r23.x); nw[3] = fmax(nw[3], mk64 + r23.y);
                    nw[4] = fmax(nw[4], mk64 + r45.x); nw[5] = fmax(nw[5], mk64 + r45.y);
                    nw[6] = fmax(nw[6], mk64 + r67.x); nw[7] = fmax(nw[7], mk64 + r67.y);
                    nw[8] = fmax(nw[8], mk64 + r8);
                }
            }
            #pragma unroll
            for (int j = 0; j < LTAGS; ++j) {
                M[j] = mk ? (nw[j] + lg[j]) : M[j];
                lg[j] = lgN[j];
            }
            mk = mkN;
        }
        double* dst = wsVM + ((size_t)b * 64 + c) * 90 + (size_t)i * 10;
        #pragma unroll
        for (int j = 0; j < LTAGS; ++j) dst[j] = M[j];
    } else if (tid >= 128 && tid < 164) {
        // ---- alpha chunk rows ----
        const int idx = tid - 128;
        const int cl = idx / 9, i = idx - 9 * cl;
        const int c  = jw * 4 + cl;

        float M[LTAGS];
        #pragma unroll
        for (int j = 0; j < LTAGS; ++j) M[j] = (i == j) ? 0.f : -1e30f;

        const double* lrow = logitsD + ((size_t)b * TLEN + (c * 16 + 1)) * LTAGS;
        const int t0 = c * 16 + 1;

        float lg[LTAGS], lgN[LTAGS];
        #pragma unroll
        for (int j = 0; j < LTAGS; ++j) lg[j] = (float)lrow[j];
        bool mk = (am[t0] != 0) && (lab[t0] != -100);

        for (int s = 0; s < 16; ++s) {
            bool mkN = false;
            const int tn = t0 + s + 1;
            if (s < 15 && tn <= TLEN - 1) {
                const double* ln = lrow + (s + 1) * LTAGS;
                #pragma unroll
                for (int j = 0; j < LTAGS; ++j) lgN[j] = (float)ln[j];
                mkN = (am[tn] != 0) && (lab[tn] != -100);
            }
            float m = M[0];
            #pragma unroll
            for (int k = 1; k < LTAGS; ++k) m = fmaxf(m, M[k]);
            float P[LTAGS];
            #pragma unroll
            for (int k = 0; k < LTAGS; ++k) P[k] = __expf(M[k] - m);
            float sa[LTAGS];
            #pragma unroll
            for (int k = 0; k < LTAGS; ++k) {
                const float4* r = (const float4*)&sE32[k * 12];
                const float4 f03 = r[0], f47 = r[1];
                const float f8 = sE32[k * 12 + 8];
                const float pk = P[k];
                if (k == 0) {
                    sa[0] = pk * f03.x; sa[1] = pk * f03.y; sa[2] = pk * f03.z; sa[3] = pk * f03.w;
                    sa[4] = pk * f47.x; sa[5] = pk * f47.y; sa[6] = pk * f47.z; sa[7] = pk * f47.w;
                    sa[8] = pk * f8;
                } else {
                    sa[0] = fmaf(pk, f03.x, sa[0]); sa[1] = fmaf(pk, f03.y, sa[1]);
                    sa[2] = fmaf(pk, f03.z, sa[2]); sa[3] = fmaf(pk, f03.w, sa[3]);
                    sa[4] = fmaf(pk, f47.x, sa[4]); sa[5] = fmaf(pk, f47.y, sa[5]);
                    sa[6] = fmaf(pk, f47.z, sa[6]); sa[7] = fmaf(pk, f47.w, sa[7]);
                    sa[8] = fmaf(pk, f8,    sa[8]);
                }
            }
            #pragma unroll
            for (int j = 0; j < LTAGS; ++j) {
                float nwj = m + __logf(sa[j]) + lg[j];
                M[j] = mk ? nwj : M[j];
                lg[j] = lgN[j];
            }
            mk = mkN;
        }
        float* dst = wsAM + (((size_t)b * 32 + c) * LTAGS + i) * LTAGS;
        #pragma unroll
        for (int j = 0; j < LTAGS; ++j) dst[j] = M[j];
    } else if (tid >= 192) {
        // ---- numerator partial: one t per thread, window [jw*64, jw*64+64) ----
        const int lane = tid - 192;              // wave 3, lanes 0..63
        const int t = jw * 64 + lane;
        const double* lrowb = logitsD + (size_t)b * TLEN * LTAGS;
        double part = 0.0;
        {
            int lv = lab[t], av = am[t];
            bool mkc = (av != 0) && (lv != -100);
            int tg = (lv == -100) ? 0 : lv;
            if (mkc) part += lrowb[(size_t)t * LTAGS + tg];
            if (t < TLEN - 1) {
                int lv2 = lab[t + 1], av2 = am[t + 1];
                bool mk2 = (av2 != 0) && (lv2 != -100);
                int tg2 = (lv2 == -100) ? 0 : lv2;
                if (mk2) part += sT64[tg * 10 + tg2];
            }
        }
        #pragma unroll
        for (int off = 32; off > 0; off >>= 1) part += __shfl_down(part, off);
        if (lane == 0) wsNumP[b * 8 + jw] = part;
    }
}

// ---------------------------------------------------------------------------
// Kernel B2 (crf2): per-batch block, 128 threads.  Identical to R6 except
// numerator = ordered sum of 8 window partials.  All global inputs for batch
// b are L2-local (written by blocks on the same XCD).
// ---------------------------------------------------------------------------
__global__ __launch_bounds__(128) void crf2_kernel(
    const float* __restrict__ trans, const int* __restrict__ labels,
    const int* __restrict__ att, const double* __restrict__ logitsD,
    const double* __restrict__ wsVM, const float* __restrict__ wsAM,
    const double* __restrict__ wsNumP, float* __restrict__ out)
{
    __shared__ __align__(16) double sVM[64 * 90];          // 46080 B (padded rows)
    __shared__ __align__(16) float  sAM[32 * 81];          // 10368 B
    __shared__ __align__(16) double sU[720];               // 5760 B: sSM, then sBPp
    __shared__ __align__(16) double sT64[90];              // padded k*10+j
    __shared__ unsigned char sMk[513];
    __shared__ int sTagB[65];
    __shared__ double sDen;

    const int b = blockIdx.x, tid = threadIdx.x;
    const int wave = tid >> 6, lane = tid & 63;
    const unsigned long long IDMAP = 0x876543210ull;

    // ---- stage (coalesced; L2-local via XCD affinity) ----
    const double2* gVM = (const double2*)(wsVM + (size_t)b * 5760);
    double2* sVM2 = (double2*)sVM;
    for (int i = tid; i < 2880; i += 128) sVM2[i] = gVM[i];
    const float4* gAM = (const float4*)(wsAM + (size_t)b * 2592);
    float4* sAM4 = (float4*)sAM;
    for (int i = tid; i < 648; i += 128) sAM4[i] = gAM[i];

    const int* lab = labels + b * TLEN;
    const int* am  = att + b * TLEN;
    for (int t = tid; t < TLEN; t += 128) {
        int lv = lab[t], av = am[t];
        sMk[t] = (av != 0 && lv != -100) ? 1 : 0;
    }
    if (tid == 0) sMk[TLEN] = 0;
    if (tid < 81) {
        const int k = tid / 9, j = tid - 9 * k;
        sT64[k * 10 + j] = (double)trans[tid];
    }
    __syncthreads();

    // ---- super-mats: S_g = M_{8g} (x) ... (x) M_{8g+7}, row-wise ----
    double* sSM = sU;
    if (tid < 72) {
        const int g = tid / 9, i = tid - 9 * g;
        double P[LTAGS];
        {
            const double* row = &sVM[(g * 8) * 90 + i * 10];
            #pragma unroll
            for (int j = 0; j < LTAGS; ++j) P[j] = row[j];
        }
        for (int m = g * 8 + 1; m < g * 8 + 8; ++m) {
            double np[LTAGS];
            #pragma unroll
            for (int k = 0; k < LTAGS; ++k) {
                const double2* r = (const double2*)&sVM[m * 90 + k * 10];
                const double2 r01 = r[0], r23 = r[1], r45 = r[2], r67 = r[3];
                const double r8 = sVM[m * 90 + k * 10 + 8];
                const double pk = P[k];
                if (k == 0) {
                    np[0] = pk + r01.x; np[1] = pk + r01.y;
                    np[2] = pk + r23.x; np[3] = pk + r23.y;
                    np[4] = pk + r45.x; np[5] = pk + r45.y;
                    np[6] = pk + r67.x; np[7] = pk + r67.y;
                    np[8] = pk + r8;
                } else {
                    np[0] = fmax(np[0], pk + r01.x); np[1] = fmax(np[1], pk + r01.y);
                    np[2] = fmax(np[2], pk + r23.x); np[3] = fmax(np[3], pk + r23.y);
                    np[4] = fmax(np[4], pk + r45.x); np[5] = fmax(np[5], pk + r45.y);
                    np[6] = fmax(np[6], pk + r67.x); np[7] = fmax(np[7], pk + r67.y);
                    np[8] = fmax(np[8], pk + r8);
                }
            }
            #pragma unroll
            for (int j = 0; j < LTAGS; ++j) P[j] = np[j];
        }
        double* dst = &sSM[g * 90 + i * 10];
        #pragma unroll
        for (int j = 0; j < LTAGS; ++j) dst[j] = P[j];
    }
    __syncthreads();

    unsigned long long* sBPp = (unsigned long long*)sU;   // reused after super-scan
    unsigned long long S = IDMAP;
    int lastTag = 0;

    if (wave == 0) {
        const int c = lane;             // chunk owned by this lane
        const int myg = c >> 3;
        double v[LTAGS], vS[LTAGS];
        #pragma unroll
        for (int j = 0; j < LTAGS; ++j) v[j] = logitsD[(size_t)b * TLEN * LTAGS + j];

        // ---- replicated super-scan (8 steps, broadcast LDS, no shfl) ----
        #pragma unroll
        for (int g = 0; g < 8; ++g) {
            if (g == myg) {
                #pragma unroll
                for (int j = 0; j < LTAGS; ++j) vS[j] = v[j];
            }
            double nv[LTAGS];
            #pragma unroll
            for (int k = 0; k < LTAGS; ++k) {
                const double2* r = (const double2*)&sSM[g * 90 + k * 10];
                const double2 r01 = r[0], r23 = r[1], r45 = r[2], r67 = r[3];
                const double r8 = sSM[g * 90 + k * 10 + 8];
                const double vk = v[k];
                if (k == 0) {
                    nv[0] = vk + r01.x; nv[1] = vk + r01.y;
                    nv[2] = vk + r23.x; nv[3] = vk + r23.y;
                    nv[4] = vk + r45.x; nv[5] = vk + r45.y;
                    nv[6] = vk + r67.x; nv[7] = vk + r67.y;
                    nv[8] = vk + r8;
                } else {
                    nv[0] = fmax(nv[0], vk + r01.x); nv[1] = fmax(nv[1], vk + r01.y);
                    nv[2] = fmax(nv[2], vk + r23.x); nv[3] = fmax(nv[3], vk + r23.y);
                    nv[4] = fmax(nv[4], vk + r45.x); nv[5] = fmax(nv[5], vk + r45.y);
                    nv[6] = fmax(nv[6], vk + r67.x); nv[7] = fmax(nv[7], vk + r67.y);
                    nv[8] = fmax(nv[8], vk + r8);
                }
            }
            #pragma unroll
            for (int j = 0; j < LTAGS; ++j) v[j] = nv[j];
        }
        // last tag (identical in every lane): argmax, ties -> lowest
        {
            int bi = 0; double bv = v[0];
            #pragma unroll
            for (int i = 1; i < LTAGS; ++i) if (v[i] > bv) { bv = v[i]; bi = i; }
            lastTag = bi;
        }

        // ---- catch-up: apply chunk mats 8*myg .. c-1 (<=7, per-lane) ----
        const int nCat = c & 7;
        for (int it = 0; it < nCat; ++it) {
            const int m = (c & ~7) + it;
            double nv[LTAGS];
            #pragma unroll
            for (int k = 0; k < LTAGS; ++k) {
                const double2* r = (const double2*)&sVM[m * 90 + k * 10];
                const double2 r01 = r[0], r23 = r[1], r45 = r[2], r67 = r[3];
                const double r8 = sVM[m * 90 + k * 10 + 8];
                const double vk = vS[k];
                if (k == 0) {
                    nv[0] = vk + r01.x; nv[1] = vk + r01.y;
                    nv[2] = vk + r23.x; nv[3] = vk + r23.y;
                    nv[4] = vk + r45.x; nv[5] = vk + r45.y;
                    nv[6] = vk + r67.x; nv[7] = vk + r67.y;
                    nv[8] = vk + r8;
                } else {
                    nv[0] = fmax(nv[0], vk + r01.x); nv[1] = fmax(nv[1], vk + r01.y);
                    nv[2] = fmax(nv[2], vk + r23.x); nv[3] = fmax(nv[3], vk + r23.y);
                    nv[4] = fmax(nv[4], vk + r45.x); nv[5] = fmax(nv[5], vk + r45.y);
                    nv[6] = fmax(nv[6], vk + r67.x); nv[7] = fmax(nv[7], vk + r67.y);
                    nv[8] = fmax(nv[8], vk + r8);
                }
            }
            #pragma unroll
            for (int j = 0; j < LTAGS; ++j) vS[j] = nv[j];
        }

        // ---- replay: backpointers + per-chunk composed map ----
        const double* lrow = logitsD + ((size_t)b * TLEN + (c * 8 + 1)) * LTAGS;
        double lg[LTAGS], lgN[LTAGS];
        #pragma unroll
        for (int j = 0; j < LTAGS; ++j) lg[j] = lrow[j];

        for (int s = 0; s < 8; ++s) {
            const int t = c * 8 + 1 + s;
            if (s < 7 && t + 1 <= TLEN - 1) {
                const double* ln = lrow + (s + 1) * LTAGS;
                #pragma unroll
                for (int j = 0; j < LTAGS; ++j) lgN[j] = ln[j];
            }
            const bool mk = (sMk[t] != 0);
            double bst[LTAGS];
            int bi[LTAGS];
            #pragma unroll
            for (int k = 0; k < LTAGS; ++k) {
                const double2* r = (const double2*)&sT64[k * 10];
                const double2 r01 = r[0], r23 = r[1], r45 = r[2], r67 = r[3];
                const double r8 = sT64[k * 10 + 8];
                const double vk = vS[k];
                double cnd[LTAGS];
                cnd[0] = vk + r01.x; cnd[1] = vk + r01.y;
                cnd[2] = vk + r23.x; cnd[3] = vk + r23.y;
                cnd[4] = vk + r45.x; cnd[5] = vk + r45.y;
                cnd[6] = vk + r67.x; cnd[7] = vk + r67.y;
                cnd[8] = vk + r8;
                if (k == 0) {
                    #pragma unroll
                    for (int j = 0; j < LTAGS; ++j) { bst[j] = cnd[j]; bi[j] = 0; }
                } else {
                    #pragma unroll
                    for (int j = 0; j < LTAGS; ++j) {
                        bool gt = cnd[j] > bst[j];     // strict >: ties keep lowest k
                        bst[j] = gt ? cnd[j] : bst[j];
                        bi[j]  = gt ? k : bi[j];
                    }
                }
            }
            unsigned long long pk = 0;
            #pragma unroll
            for (int j = 0; j < LTAGS; ++j)
                pk |= ((unsigned long long)bi[j]) << (4 * j);
            pk = mk ? pk : IDMAP;
            sBPp[t] = pk;
            #pragma unroll
            for (int j = 0; j < LTAGS; ++j) {
                vS[j] = mk ? (bst[j] + lg[j]) : vS[j];
                lg[j] = lgN[j];
            }
        }
        // compose chunk backtrace map
        unsigned long long G = IDMAP;
        for (int s = 7; s >= 0; --s) {
            const unsigned long long bp = sBPp[c * 8 + 1 + s];
            unsigned long long ng = 0;
            #pragma unroll
            for (int j = 0; j < LTAGS; ++j) {
                int gj = (int)((G >> (4 * j)) & 15);
                int f  = (int)((bp >> (4 * gj)) & 15);
                ng |= ((unsigned long long)f) << (4 * j);
            }
            G = ng;
        }
        S = G;
    } else {
        // ---- alpha boundary scan over 32 chunk matrices ----
        const int j = (lane < LTAGS) ? lane : (LTAGS - 1);
        float v = (float)logitsD[(size_t)b * TLEN * LTAGS + j];
        float Mc[LTAGS], Mn[LTAGS];
        #pragma unroll
        for (int i = 0; i < LTAGS; ++i) Mc[i] = sAM[i * LTAGS + j];
        for (int c = 0; c < 32; ++c) {
            if (c < 31) {
                #pragma unroll
                for (int i = 0; i < LTAGS; ++i) Mn[i] = sAM[(c + 1) * 81 + i * LTAGS + j];
            }
            float g[LTAGS];
            #pragma unroll
            for (int i = 0; i < LTAGS; ++i) g[i] = __shfl(v, i);
            float a[LTAGS];
            #pragma unroll
            for (int i = 0; i < LTAGS; ++i) a[i] = g[i] + Mc[i];
            float t01 = fmaxf(a[0], a[1]), t23 = fmaxf(a[2], a[3]);
            float t45 = fmaxf(a[4], a[5]), t67 = fmaxf(a[6], a[7]);
            float m = fmaxf(fmaxf(fmaxf(t01, t23), fmaxf(t45, t67)), a[8]);
            float sacc = 0.f;
            #pragma unroll
            for (int i = 0; i < LTAGS; ++i) sacc += __expf(a[i] - m);
            v = m + __logf(sacc);
            if (c < 31) {
                #pragma unroll
                for (int i = 0; i < LTAGS; ++i) Mc[i] = Mn[i];
            }
        }
        float g[LTAGS];
        #pragma unroll
        for (int i = 0; i < LTAGS; ++i) g[i] = __shfl(v, i);
        if (lane == 0) {
            float m = g[0];
            #pragma unroll
            for (int i = 1; i < LTAGS; ++i) m = fmaxf(m, g[i]);
            float sacc = 0.f;
            #pragma unroll
            for (int i = 0; i < LTAGS; ++i) sacc += __expf(g[i] - m);
            sDen = (double)(m + __logf(sacc));
        }
    }

    // ---- suffix composition scan via shfl: S_c = F_c o ... o F_63 ----
    #pragma unroll
    for (int d = 1; d < 64; d <<= 1) {
        unsigned long long Sn = __shfl_down(S, d);
        if (wave == 0 && lane + d < 64) {
            unsigned long long R = 0;
            #pragma unroll
            for (int x = 0; x < LTAGS; ++x) {
                int y = (int)((Sn >> (4 * x)) & 15);
                int z = (int)((S >> (4 * y)) & 15);
                R |= ((unsigned long long)z) << (4 * x);
            }
            S = R;
        }
    }
    if (wave == 0) {
        sTagB[tid] = (int)((S >> (4 * lastTag)) & 15);
        if (tid == 0) sTagB[64] = lastTag;
    }
    __syncthreads();

    // ---- chunk-parallel expansion -> predictions ----
    if (tid < 64) {
        const int c = tid;
        int cur = sTagB[c + 1];
        float* po = out + 1 + b * TLEN;
        for (int s = 8; s >= 1; --s) {
            const int t = c * 8 + s;
            if (t < TLEN) {
                int nxt = (int)((sBPp[t] >> (4 * cur)) & 15);
                po[t] = sMk[t - 1] ? (float)nxt : -100.f;
                cur = nxt;
            }
        }
    }
    if (tid == 0) {
        out[1 + b * TLEN] = -100.f;
        double num = 0.0;
        const double* np = wsNumP + b * 8;
        #pragma unroll
        for (int q = 0; q < 8; ++q) num += np[q];
        atomicAdd(out, (float)(sDen - num));   // loss (den - num)
    }
}

extern "C" void kernel_launch(void* const* d_in, const int* in_sizes, int n_in,
                              void* d_out, int out_size, void* d_ws, size_t ws_size,
                              hipStream_t stream)
{
    const float* hidden = (const float*)d_in[0];
    const float* W      = (const float*)d_in[1];
    const float* bvec   = (const float*)d_in[2];
    const float* trans  = (const float*)d_in[3];
    const int*   labels = (const int*)d_in[4];
    const int*   att    = (const int*)d_in[5];
    float* out = (float*)d_out;

    char* ws = (char*)d_ws;
    double* logitsD = (double*)(ws + WS_LOGD);
    double* wsVM    = (double*)(ws + WS_VM);
    float*  wsAM    = (float*)(ws + WS_AM);
    double* wsNumP  = (double*)(ws + WS_NUMP);

    logits_kernel<<<512, 256, 0, stream>>>(hidden, W, bvec, logitsD, out);
    chunk_kernel<<<512, 256, 0, stream>>>(trans, labels, att, logitsD,
                                          wsVM, wsAM, wsNumP);
    crf2_kernel<<<BATCH, 128, 0, stream>>>(trans, labels, att, logitsD,
                                           wsVM, wsAM, wsNumP, out);
}